// Round 7
// baseline (119.448 us; speedup 1.0000x reference)
//
#include <hip/hip_runtime.h>

typedef _Float16 f16;
typedef __attribute__((ext_vector_type(2))) _Float16 f16x2;
typedef __attribute__((ext_vector_type(4))) _Float16 f16x4;
typedef __attribute__((ext_vector_type(8))) _Float16 f16x8;
typedef __attribute__((ext_vector_type(2))) __fp16 fp16x2_raw;
typedef __attribute__((ext_vector_type(4))) float f32x4;

#define MFMA32(a,b,c) __builtin_amdgcn_mfma_f32_16x16x32_f16((a),(b),(c),0,0,0)
#define MFMA16(a,b,c) __builtin_amdgcn_mfma_f32_16x16x16f16((a),(b),(c),0,0,0)

__device__ __forceinline__ f16x2 cvt2(float a, float b) {
    fp16x2_raw v = __builtin_amdgcn_cvt_pkrtz(a, b);
    f16x2 r; __builtin_memcpy(&r, &v, sizeof(r));
    return r;
}

// ---- pre-kernel: pack W{q,k,v,p} into per-lane f16 A-fragments in ws.
// frag c = m*8 + ob*2 + s (m: 0=q 1=k 2=v 3=p); lane l holds row ob*16+(l&15),
// k = 8*(l>>4) + 32*s + [0,8). Main-kernel loads: 16B/lane coalesced, L2-resident.
__global__ void wprep(const float* __restrict__ Wq, const float* __restrict__ Wk,
                      const float* __restrict__ Wv, const float* __restrict__ Wp,
                      f16* __restrict__ ws)
{
    const int t = threadIdx.x;
    const int lane = t & 63;
    const float* Wm[4] = {Wq, Wk, Wv, Wp};
    #pragma unroll
    for (int j = 0; j < 8; ++j) {
        const int c = (t >> 6) * 8 + j;
        const int m = c >> 3, ob = (c >> 1) & 3, s = c & 1;
        const float* src = Wm[m] + (ob * 16 + (lane & 15)) * 64 + 8 * (lane >> 4) + 32 * s;
        f32x4 a4 = *(const f32x4*)src;
        f32x4 b4 = *(const f32x4*)(src + 4);
        f16x8 h;
        #pragma unroll
        for (int ii = 0; ii < 8; ++ii) h[ii] = (f16)(ii < 4 ? a4[ii] : b4[ii - 4]);
        *(f16x8*)(ws + c * 512 + lane * 8) = h;
    }
}

// One block = 4 consecutive-iw windows; wave w owns window w end-to-end.
// LDS 32,768 B total:
//   XW: per-window 8KB tile: xw[64t][64c] -> vv[64c][64t] -> o_t[64t][64c]
//       (aliased, wave-private after B1; addr(row,col)=row*64+((col>>3 ^ row&7 ^ win)<<3)+(col&7))
//   SG: f32 out-staging ALIASES XW base (17,472B) — af hoisted to regs behind B_af first.
// P lives in registers (swapped-S^T D-layout == K16 PV B-frag layout).
__global__ __launch_bounds__(256, 4)
void wsa3d(const float* __restrict__ x, const f16* __restrict__ wsf,
           const float* __restrict__ bq, const float* __restrict__ bk,
           const float* __restrict__ bv, const float* __restrict__ bp,
           float* __restrict__ out)
{
    __shared__ __align__(16) f16 lds[16384];
    f16*   const XW = lds;
    float* const SG = (float*)lds;

    const int tid  = threadIdx.x;
    const int lane = tid & 63;
    const int w    = tid >> 6;
    const int g    = lane >> 4;
    const int ln16 = lane & 15;
    const int key  = ln16 & 7;

    // XCD swizzle (2048 % 8 == 0 -> bijective): 256 consecutive quads per XCD
    const int bid = blockIdx.x;
    const int Q   = ((bid & 7) << 8) | (bid >> 3);
    const int qx = Q & 3, ih = (Q >> 2) & 15, idz = (Q >> 6) & 15, b = Q >> 10;

    const float c_sc = 0.25f * 1.44269504088896340736f;  // scale * log2(e)
    const f32x4 z4 = {0.f, 0.f, 0.f, 0.f};

    const int gz = (lane >> 4) & 3, gy = (lane >> 2) & 3, gq = lane & 3;

    // ---- gather (coalesced, 16 lines/inst); immediate f16 conversion (VGPR diet)
    f16x4 valh[16];
    #pragma unroll
    for (int i = 0; i < 16; ++i) {
        const int c = w * 16 + i;
        f32x4 v4 = *(const f32x4*)(x + ((((b*64 + c)*64 + idz*4 + gz)*64) + ih*4 + gy)*64 + qx*16 + gq*4);
        f16x2 lo = cvt2(v4[0], v4[1]), hi = cvt2(v4[2], v4[3]);
        valh[i] = f16x4{lo[0], lo[1], hi[0], hi[1]};
    }
    // ---- all bias loads issued here (hidden under gather latency)
    f32x4 bqv[4], bkv[4];
    float bvs4[4], bps4[4];
    #pragma unroll
    for (int h = 0; h < 4; ++h) {
        bqv[h] = *(const f32x4*)(bq + h * 16 + g * 4);
        bkv[h] = *(const f32x4*)(bk + h * 16 + g * 4);
        bvs4[h] = bv[h * 16 + ln16];
        bps4[h] = bp[h * 16 + ln16];
    }

    // ---- transpose-pack -> xw of window gq (wave w supplies channels [16w,16w+16))
    #pragma unroll
    for (int lx = 0; lx < 4; ++lx) {
        const int t = gz * 16 + gy * 4 + lx;
        #pragma unroll
        for (int h2 = 0; h2 < 2; ++h2) {
            f16x8 pk;
            #pragma unroll
            for (int ii = 0; ii < 8; ++ii) pk[ii] = valh[h2 * 8 + ii][lx];
            *(f16x8*)(XW + gq*4096 + t*64 + (((w*2 + h2) ^ (t & 7) ^ gq) << 3)) = pk;
        }
    }
    __syncthreads();   // B1

    // ---- xw fragments (B for q/k proj, A for v^T proj)
    f16x8 xf[4][2];
    #pragma unroll
    for (int lb = 0; lb < 4; ++lb)
        #pragma unroll
        for (int s = 0; s < 2; ++s)
            xf[lb][s] = *(const f16x8*)(XW + w*4096 + (lb*16 + ln16)*64 + (((g + 4*s) ^ key ^ w) << 3));

    // ---- prefetch head 0 Wq/Wk fragments (hidden under vproj)
    f16x8 QF[2], KF[2];
    #pragma unroll
    for (int s = 0; s < 2; ++s) {
        QF[s] = *(const f16x8*)(wsf + (0*2 + s)*512 + lane*8);
        KF[s] = *(const f16x8*)(wsf + (8 + 0*2 + s)*512 + lane*8);
    }

    // ---- v^T projection -> vv[ch][tok] (same-wave overwrite of xw)
    #pragma unroll
    for (int ob = 0; ob < 4; ++ob) {
        f16x8 VF[2];
        #pragma unroll
        for (int s = 0; s < 2; ++s) VF[s] = *(const f16x8*)(wsf + (16 + ob*2 + s)*512 + lane*8);
        #pragma unroll
        for (int tb = 0; tb < 4; ++tb) {
            f32x4 a = z4;
            #pragma unroll
            for (int s = 0; s < 2; ++s) a = MFMA32(xf[tb][s], VF[s], a);
            f16x4 h4;
            #pragma unroll
            for (int r = 0; r < 4; ++r) h4[r] = (f16)(a[r] + bvs4[ob]);
            *(f16x4*)(XW + w*4096 + (ob*16 + ln16)*64 + (((2*tb + (g >> 1)) ^ key ^ w) << 3) + 4*(g & 1)) = h4;
        }
    }

    // ---- attention, head-sequential; P in registers; W-frag prefetch 1 head ahead
    f16x4 ot[4][4];
    #pragma unroll
    for (int h = 0; h < 4; ++h) {
        // q/k proj: C-layout == K16 frag layout (lane: d=4g+r, tok=16lb+ln16)
        f16x4 qf[4], kf[4];
        #pragma unroll
        for (int lb = 0; lb < 4; ++lb) {
            f32x4 aq = z4, ak = z4;
            #pragma unroll
            for (int s = 0; s < 2; ++s) {
                aq = MFMA32(QF[s], xf[lb][s], aq);
                ak = MFMA32(KF[s], xf[lb][s], ak);
            }
            #pragma unroll
            for (int r = 0; r < 4; ++r) {
                qf[lb][r] = (f16)((aq[r] + bqv[h][r]) * c_sc);
                kf[lb][r] = (f16)(ak[r] + bkv[h][r]);
            }
        }
        if (h < 3) {   // prefetch next head's fragments (hidden under S^T/exp/PV)
            #pragma unroll
            for (int s = 0; s < 2; ++s) {
                QF[s] = *(const f16x8*)(wsf + ((h+1)*2 + s)*512 + lane*8);
                KF[s] = *(const f16x8*)(wsf + (8 + (h+1)*2 + s)*512 + lane*8);
            }
        }
        // v A-fragments: row d = ch 16h+ln16, k = j = 16jb+4g+ii
        f16x4 va[4];
        #pragma unroll
        for (int jb = 0; jb < 4; ++jb)
            va[jb] = *(const f16x4*)(XW + w*4096 + (16*h + ln16)*64 + (((2*jb + (g >> 1)) ^ key ^ w) << 3) + 4*(g & 1));
        #pragma unroll
        for (int ib = 0; ib < 4; ++ib) {
            f32x4 e[4];
            #pragma unroll
            for (int jb = 0; jb < 4; ++jb) {
                f32x4 S = MFMA16(kf[jb], qf[ib], z4);   // S^T: row=j(16jb+4g+r), col=i(16ib+ln16)
                #pragma unroll
                for (int r = 0; r < 4; ++r) e[jb][r] = __builtin_amdgcn_exp2f(S[r]);
            }
            f32x4 s4 = e[0] + e[1] + e[2] + e[3];
            float hh = (s4[0] + s4[1]) + (s4[2] + s4[3]);
            hh += __shfl_xor(hh, 16);
            hh += __shfl_xor(hh, 32);
            const float inv = __builtin_amdgcn_rcpf(hh);
            f32x4 O = z4;
            #pragma unroll
            for (int jb = 0; jb < 4; ++jb) {
                f16x4 pf;
                #pragma unroll
                for (int r = 0; r < 4; ++r) pf[r] = (f16)e[jb][r];
                O = MFMA16(va[jb], pf, O);              // row=d(4g+r), col=i(16ib+ln16)
            }
            #pragma unroll
            for (int r = 0; r < 4; ++r) ot[h][ib][r] = (f16)(O[r] * inv);
        }
    }

    // ---- o_t[tok][ch] stores (vv dead; same-wave ordering)
    #pragma unroll
    for (int h = 0; h < 4; ++h)
        #pragma unroll
        for (int ib = 0; ib < 4; ++ib)
            *(f16x4*)(XW + w*4096 + (16*ib + ln16)*64 + (((2*h + (g >> 1)) ^ key ^ w) << 3) + 4*(g & 1)) = ot[h][ib];

    // ---- hoist o_t fragments + all Wp fragments, then XW becomes staging
    f16x8 af[4][2];
    #pragma unroll
    for (int tb = 0; tb < 4; ++tb)
        #pragma unroll
        for (int s = 0; s < 2; ++s)
            af[tb][s] = *(const f16x8*)(XW + w*4096 + (tb*16 + ln16)*64 + (((g + 4*s) ^ key ^ w) << 3));
    f16x8 PF[4][2];
    #pragma unroll
    for (int oc = 0; oc < 4; ++oc)
        #pragma unroll
        for (int s = 0; s < 2; ++s) PF[oc][s] = *(const f16x8*)(wsf + (24 + oc*2 + s)*512 + lane*8);
    __syncthreads();   // B_af: all o_t reads done -> XW reusable as f32 staging

    // ---- per-oc: out-proj (lane: t=tb*16+4g+r, o=oc*16+ln16) -> stage -> coalesced scatter
    #pragma unroll
    for (int oc = 0; oc < 4; ++oc) {
        #pragma unroll
        for (int tb = 0; tb < 4; ++tb) {
            f32x4 a = z4;
            #pragma unroll
            for (int s = 0; s < 2; ++s) a = MFMA32(af[tb][s], PF[oc][s], a);
            #pragma unroll
            for (int r = 0; r < 4; ++r) a[r] += bps4[oc];
            *(f32x4*)(SG + w*1092 + ln16*68 + ((tb*16 + g*4) ^ (w << 2))) = a;
        }
        __syncthreads();
        #pragma unroll
        for (int si = 0; si < 4; ++si) {
            const int o2 = w * 4 + si;
            f32x4 v4 = *(const f32x4*)(SG + gq*1092 + o2*68 + ((gz*16 + gy*4) ^ (gq << 2)));
            *(f32x4*)(out + ((((b*64 + oc*16 + o2)*64 + idz*4 + gz)*64) + ih*4 + gy)*64 + qx*16 + gq*4) = v4;
        }
        if (oc < 3) __syncthreads();
    }
}

extern "C" void kernel_launch(void* const* d_in, const int* in_sizes, int n_in,
                              void* d_out, int out_size, void* d_ws, size_t ws_size,
                              hipStream_t stream) {
    (void)in_sizes; (void)n_in; (void)out_size; (void)ws_size;
    const float* x  = (const float*)d_in[0];
    const float* Wq = (const float*)d_in[1];
    const float* bq = (const float*)d_in[2];
    const float* Wk = (const float*)d_in[3];
    const float* bk = (const float*)d_in[4];
    const float* Wv = (const float*)d_in[5];
    const float* bv = (const float*)d_in[6];
    const float* Wp = (const float*)d_in[7];
    const float* bp = (const float*)d_in[8];
    f16* wsf = (f16*)d_ws;
    wprep<<<1, 256, 0, stream>>>(Wq, Wk, Wv, Wp, wsf);
    wsa3d<<<2048, 256, 0, stream>>>(x, wsf, bq, bk, bv, bp, (float*)d_out);
}

// Round 8
// 67.643 us; speedup vs baseline: 1.7659x; 1.7659x over previous
//
#include <hip/hip_runtime.h>

typedef _Float16 f16;
typedef __attribute__((ext_vector_type(4))) _Float16 f16x4;
typedef __attribute__((ext_vector_type(8))) _Float16 f16x8;
typedef __attribute__((ext_vector_type(4))) float f32x4;

#define MFMA32(a,b,c) __builtin_amdgcn_mfma_f32_16x16x32_f16((a),(b),(c),0,0,0)
#define MFMA16(a,b,c) __builtin_amdgcn_mfma_f32_16x16x16f16((a),(b),(c),0,0,0)

// ---- pre-kernel: pack W{q,k,v,p} into per-lane f16 A-fragments in ws.
// frag c = m*8 + ob*2 + s (m: 0=q 1=k 2=v 3=p); lane l holds row ob*16+(l&15),
// k = 8*(l>>4) + 32*s + [0,8). Main-kernel loads: 16B/lane coalesced, L2-resident.
__global__ void wprep(const float* __restrict__ Wq, const float* __restrict__ Wk,
                      const float* __restrict__ Wv, const float* __restrict__ Wp,
                      f16* __restrict__ ws)
{
    const int t = threadIdx.x;
    const int lane = t & 63;
    const float* Wm[4] = {Wq, Wk, Wv, Wp};
    #pragma unroll
    for (int j = 0; j < 8; ++j) {
        const int c = (t >> 6) * 8 + j;
        const int m = c >> 3, ob = (c >> 1) & 3, s = c & 1;
        const float* src = Wm[m] + (ob * 16 + (lane & 15)) * 64 + 8 * (lane >> 4) + 32 * s;
        f32x4 a4 = *(const f32x4*)src;
        f32x4 b4 = *(const f32x4*)(src + 4);
        f16x8 h;
        #pragma unroll
        for (int ii = 0; ii < 8; ++ii) h[ii] = (f16)(ii < 4 ? a4[ii] : b4[ii - 4]);
        *(f16x8*)(ws + c * 512 + lane * 8) = h;
    }
}

// One block = 4 consecutive-iw windows; wave w owns window w end-to-end.
// LDS 32,768 B:
//   XW: per-window 8KB tile: xw[64t][64c] -> vv[64c][64t] -> o_t[64t][64c]
//       (aliased, wave-private after B1; addr(row,col)=row*64+((col>>3 ^ row&7 ^ win)<<3)+(col&7))
//   SG: f32 out-staging (17,472B) ALIASES XW — legal because res[4][4] (the last XW
//       reads) is fully computed before B_alias, after which XW is dead.
// P lives in registers (swapped-S^T D-layout == K16 PV B-frag layout).
// launch_bounds min-waves=3: R7 proved 4 forces spills (VGPR+AGPR unified budget).
__global__ __launch_bounds__(256, 3)
void wsa3d(const float* __restrict__ x, const f16* __restrict__ wsf,
           const float* __restrict__ bq, const float* __restrict__ bk,
           const float* __restrict__ bv, const float* __restrict__ bp,
           float* __restrict__ out)
{
    __shared__ __align__(16) f16 lds[16384];
    f16*   const XW = lds;
    float* const SG = (float*)lds;

    const int tid  = threadIdx.x;
    const int lane = tid & 63;
    const int w    = tid >> 6;
    const int g    = lane >> 4;
    const int ln16 = lane & 15;
    const int key  = ln16 & 7;

    // XCD swizzle (2048 % 8 == 0 -> bijective): 256 consecutive quads per XCD
    const int bid = blockIdx.x;
    const int Q   = ((bid & 7) << 8) | (bid >> 3);
    const int qx = Q & 3, ih = (Q >> 2) & 15, idz = (Q >> 6) & 15, b = Q >> 10;

    const float c_sc = 0.25f * 1.44269504088896340736f;  // scale * log2(e)
    const f32x4 z4 = {0.f, 0.f, 0.f, 0.f};

    const int gz = (lane >> 4) & 3, gy = (lane >> 2) & 3, gq = lane & 3;

    // ---- gather (coalesced, 16 lines/inst); immediate f16 convert (gather-phase
    //      peak pressure 64 f32 regs -> 16)
    f16x4 valh[16];
    #pragma unroll
    for (int i = 0; i < 16; ++i) {
        const int c = w * 16 + i;
        f32x4 v4 = *(const f32x4*)(x + ((((b*64 + c)*64 + idz*4 + gz)*64) + ih*4 + gy)*64 + qx*16 + gq*4);
        #pragma unroll
        for (int r = 0; r < 4; ++r) valh[i][r] = (f16)v4[r];
    }

    // ---- transpose-pack -> xw of window gq (wave w supplies channels [16w,16w+16))
    #pragma unroll
    for (int lx = 0; lx < 4; ++lx) {
        const int t = gz * 16 + gy * 4 + lx;
        #pragma unroll
        for (int h2 = 0; h2 < 2; ++h2) {
            f16x8 pk;
            #pragma unroll
            for (int ii = 0; ii < 8; ++ii) pk[ii] = valh[h2 * 8 + ii][lx];
            *(f16x8*)(XW + gq*4096 + t*64 + (((w*2 + h2) ^ (t & 7) ^ gq) << 3)) = pk;
        }
    }
    __syncthreads();   // B1

    // ---- xw fragments (B for q/k proj, A for v^T proj)
    f16x8 xf[4][2];
    #pragma unroll
    for (int lb = 0; lb < 4; ++lb)
        #pragma unroll
        for (int s = 0; s < 2; ++s)
            xf[lb][s] = *(const f16x8*)(XW + w*4096 + (lb*16 + ln16)*64 + (((g + 4*s) ^ key ^ w) << 3));

    // ---- v^T projection -> vv[ch][tok] (same-wave overwrite of xw)
    #pragma unroll
    for (int ob = 0; ob < 4; ++ob) {
        f16x8 VF[2];
        #pragma unroll
        for (int s = 0; s < 2; ++s) VF[s] = *(const f16x8*)(wsf + (16 + ob*2 + s)*512 + lane*8);
        const float bvo = bv[ob * 16 + ln16];
        #pragma unroll
        for (int tb = 0; tb < 4; ++tb) {
            f32x4 a = z4;
            #pragma unroll
            for (int s = 0; s < 2; ++s) a = MFMA32(xf[tb][s], VF[s], a);
            f16x4 h4;
            #pragma unroll
            for (int r = 0; r < 4; ++r) h4[r] = (f16)(a[r] + bvo);
            *(f16x4*)(XW + w*4096 + (ob*16 + ln16)*64 + (((2*tb + (g >> 1)) ^ key ^ w) << 3) + 4*(g & 1)) = h4;
        }
    }

    // ---- attention, head-sequential, P fully in registers
    f16x4 ot[4][4];
    #pragma unroll
    for (int h = 0; h < 4; ++h) {
        f16x8 QF[2], KF[2];
        #pragma unroll
        for (int s = 0; s < 2; ++s) {
            QF[s] = *(const f16x8*)(wsf + (h*2 + s)*512 + lane*8);
            KF[s] = *(const f16x8*)(wsf + (8 + h*2 + s)*512 + lane*8);
        }
        const f32x4 bqv = *(const f32x4*)(bq + h*16 + g*4);
        const f32x4 bkv = *(const f32x4*)(bk + h*16 + g*4);
        // q/k proj: C-layout == K16 frag layout (lane: d=4g+r, tok=16lb+ln16)
        f16x4 qf[4], kf[4];
        #pragma unroll
        for (int lb = 0; lb < 4; ++lb) {
            f32x4 aq = z4, ak = z4;
            #pragma unroll
            for (int s = 0; s < 2; ++s) {
                aq = MFMA32(QF[s], xf[lb][s], aq);
                ak = MFMA32(KF[s], xf[lb][s], ak);
            }
            #pragma unroll
            for (int r = 0; r < 4; ++r) {
                qf[lb][r] = (f16)((aq[r] + bqv[r]) * c_sc);
                kf[lb][r] = (f16)(ak[r] + bkv[r]);
            }
        }
        // v A-fragments: row d = ch 16h+ln16, k = j = 16jb+4g+ii
        f16x4 va[4];
        #pragma unroll
        for (int jb = 0; jb < 4; ++jb)
            va[jb] = *(const f16x4*)(XW + w*4096 + (16*h + ln16)*64 + (((2*jb + (g >> 1)) ^ key ^ w) << 3) + 4*(g & 1));
        #pragma unroll
        for (int ib = 0; ib < 4; ++ib) {
            f32x4 e[4];
            #pragma unroll
            for (int jb = 0; jb < 4; ++jb) {
                f32x4 S = MFMA16(kf[jb], qf[ib], z4);   // S^T: row=j(16jb+4g+r), col=i(16ib+ln16)
                #pragma unroll
                for (int r = 0; r < 4; ++r) e[jb][r] = __builtin_amdgcn_exp2f(S[r]);
            }
            f32x4 s4 = e[0] + e[1] + e[2] + e[3];
            float hh = (s4[0] + s4[1]) + (s4[2] + s4[3]);
            hh += __shfl_xor(hh, 16);
            hh += __shfl_xor(hh, 32);
            const float inv = __builtin_amdgcn_rcpf(hh);
            f32x4 O = z4;
            #pragma unroll
            for (int jb = 0; jb < 4; ++jb) {
                f16x4 pf;
                #pragma unroll
                for (int r = 0; r < 4; ++r) pf[r] = (f16)e[jb][r];
                O = MFMA16(va[jb], pf, O);              // row=d(4g+r), col=i(16ib+ln16)
            }
            #pragma unroll
            for (int r = 0; r < 4; ++r) ot[h][ib][r] = (f16)(O[r] * inv);
        }
    }

    // ---- o_t[tok][ch] stores (vv dead; same-wave ordering)
    #pragma unroll
    for (int h = 0; h < 4; ++h)
        #pragma unroll
        for (int ib = 0; ib < 4; ++ib)
            *(f16x4*)(XW + w*4096 + (16*ib + ln16)*64 + (((2*h + (g >> 1)) ^ key ^ w) << 3) + 4*(g & 1)) = ot[h][ib];

    // ---- output projection: D2[t][o] = sum_c o_t[t][c] Wp[o][c]  (reads XW; last use)
    f16x8 PF[4][2];
    #pragma unroll
    for (int oc = 0; oc < 4; ++oc)
        #pragma unroll
        for (int s = 0; s < 2; ++s) PF[oc][s] = *(const f16x8*)(wsf + (24 + oc*2 + s)*512 + lane*8);
    float bps[4];
    #pragma unroll
    for (int oc = 0; oc < 4; ++oc) bps[oc] = bp[oc * 16 + ln16];

    f32x4 res[4][4];
    #pragma unroll
    for (int tb = 0; tb < 4; ++tb) {
        f16x8 af[2];
        #pragma unroll
        for (int s = 0; s < 2; ++s)
            af[s] = *(const f16x8*)(XW + w*4096 + (tb*16 + ln16)*64 + (((g + 4*s) ^ key ^ w) << 3));
        #pragma unroll
        for (int oc = 0; oc < 4; ++oc) {
            f32x4 a = z4;
            #pragma unroll
            for (int s = 0; s < 2; ++s) a = MFMA32(af[s], PF[oc][s], a);
            #pragma unroll
            for (int r = 0; r < 4; ++r) res[tb][oc][r] = a[r] + bps[oc];
        }
    }
    __syncthreads();   // B_alias: all XW reads done (all waves) -> XW reusable as SG

    // ---- staged, coalesced scatter (4 oc rounds)
    #pragma unroll
    for (int oc = 0; oc < 4; ++oc) {
        #pragma unroll
        for (int tb = 0; tb < 4; ++tb)
            *(f32x4*)(SG + w*1092 + ln16*68 + ((tb*16 + g*4) ^ (w << 2))) = res[tb][oc];
        __syncthreads();
        #pragma unroll
        for (int si = 0; si < 4; ++si) {
            const int o2 = w * 4 + si;
            f32x4 v4 = *(const f32x4*)(SG + gq*1092 + o2*68 + ((gz*16 + gy*4) ^ (gq << 2)));
            *(f32x4*)(out + ((((b*64 + oc*16 + o2)*64 + idz*4 + gz)*64) + ih*4 + gy)*64 + qx*16 + gq*4) = v4;
        }
        if (oc < 3) __syncthreads();
    }
}

extern "C" void kernel_launch(void* const* d_in, const int* in_sizes, int n_in,
                              void* d_out, int out_size, void* d_ws, size_t ws_size,
                              hipStream_t stream) {
    (void)in_sizes; (void)n_in; (void)out_size; (void)ws_size;
    const float* x  = (const float*)d_in[0];
    const float* Wq = (const float*)d_in[1];
    const float* bq = (const float*)d_in[2];
    const float* Wk = (const float*)d_in[3];
    const float* bk = (const float*)d_in[4];
    const float* Wv = (const float*)d_in[5];
    const float* bv = (const float*)d_in[6];
    const float* Wp = (const float*)d_in[7];
    const float* bp = (const float*)d_in[8];
    f16* wsf = (f16*)d_ws;
    wprep<<<1, 256, 0, stream>>>(Wq, Wk, Wv, Wp, wsf);
    wsa3d<<<2048, 256, 0, stream>>>(x, wsf, bq, bk, bv, bp, (float*)d_out);
}